// Round 1
// 458.227 us; speedup vs baseline: 1.2839x; 1.2839x over previous
//
#include <hip/hip_runtime.h>
#include <stdint.h>
#include <stddef.h>

// Problem constants
#define DM 1024        // d_model
#define NS 16          // d_state
#define TOK 32768      // B*S = 8*4096
#define SEQ 4096

typedef unsigned short ushort_t;
typedef __attribute__((ext_vector_type(4))) float f32x4;
typedef __attribute__((ext_vector_type(8))) short short8;

// ---------- f32 -> bf16 (RNE) packing helpers ----------
__device__ __forceinline__ float bf2f(unsigned int u) {
    union { unsigned int i; float f; } x; x.i = u << 16; return x.f;
}
__device__ __forceinline__ unsigned short f2bf(float f) {
    union { float f; unsigned int i; } x; x.f = f;
    unsigned int r = x.i + 0x7fffu + ((x.i >> 16) & 1u);
    return (unsigned short)(r >> 16);
}
__device__ __forceinline__ unsigned int pack2(float lo, float hi) {
    return (unsigned int)f2bf(lo) | ((unsigned int)f2bf(hi) << 16);
}
__device__ __forceinline__ uint4 cvt8u(float4 a, float4 b) {
    uint4 u;
    u.x = pack2(a.x, a.y); u.y = pack2(a.z, a.w);
    u.z = pack2(b.x, b.y); u.w = pack2(b.z, b.w);
    return u;
}

// async global->LDS, 16B per lane (global_load_lds_dwordx4).
// LDS dest must be wave-uniform base + lane*16 (m104/m108) — our chunk
// mapping (c = tid) satisfies this exactly.
__device__ __forceinline__ void async_lds16(void* lds, const void* g) {
    __builtin_amdgcn_global_load_lds(
        (__attribute__((address_space(1))) void*)(g),
        (__attribute__((address_space(3))) void*)(lds),
        16, 0, 0);
}

// ---------------------------------------------------------------------------
// K0: pre-scale weights by ln_w; build LN-fold vectors.  (f32 inputs)
//   rows 0..1023   : Wpg[e][:]  = bf16(Wg[e][:]*w); s1g[e]=sum(w*Wg); s2g[e]=sum(b*Wg)
//   rows 1024..1039: Wpsi[n][:] = bf16((Ws+Wi)[n][:]*w); s1u[n]; d1u[n]=sum(b*(Ws+Wi))+bs+bi
// ---------------------------------------------------------------------------
__global__ __launch_bounds__(256) void k_prep(
    const float* __restrict__ Wg, const float* __restrict__ Ws,
    const float* __restrict__ Wi, const float* __restrict__ lw,
    const float* __restrict__ lb, const float* __restrict__ bs,
    const float* __restrict__ bi,
    ushort_t* __restrict__ Wpg, ushort_t* __restrict__ Wpsi,
    float* __restrict__ s1g, float* __restrict__ s2g,
    float* __restrict__ s1u, float* __restrict__ d1u)
{
    int wv = threadIdx.x >> 6, lane = threadIdx.x & 63;
    int row = blockIdx.x * 4 + wv;
    if (row >= DM + NS) return;

    const float4* lwr = (const float4*)lw;
    const float4* lbr = (const float4*)lb;

    float s1 = 0.f, s2 = 0.f;
    ushort_t* dstrow;
    const float4* wr0 = nullptr;
    const float4* wr1 = nullptr;
    int n = row - DM;
    if (row < DM) {
        wr0 = (const float4*)(Wg + (size_t)row * DM);
        dstrow = Wpg + (size_t)row * DM;
    } else {
        wr0 = (const float4*)(Ws + (size_t)n * DM);
        wr1 = (const float4*)(Wi + (size_t)n * DM);
        dstrow = Wpsi + (size_t)n * DM;
    }
    uint2* dst2 = (uint2*)dstrow;

#pragma unroll
    for (int j = 0; j < 4; j++) {
        int idx = j * 64 + lane;
        float4 w4 = lwr[idx];
        float4 b4 = lbr[idx];
        float4 g4 = wr0[idx];
        if (wr1) {
            float4 g1 = wr1[idx];
            g4.x += g1.x; g4.y += g1.y; g4.z += g1.z; g4.w += g1.w;
        }
        float p0 = g4.x * w4.x, p1 = g4.y * w4.y;
        float p2 = g4.z * w4.z, p3 = g4.w * w4.w;
        s1 += p0 + p1 + p2 + p3;
        s2 += g4.x * b4.x + g4.y * b4.y + g4.z * b4.z + g4.w * b4.w;
        uint2 o; o.x = pack2(p0, p1); o.y = pack2(p2, p3);
        dst2[idx] = o;
    }
#pragma unroll
    for (int off = 32; off >= 1; off >>= 1) {
        s1 += __shfl_xor(s1, off);
        s2 += __shfl_xor(s2, off);
    }
    if (lane == 0) {
        if (row < DM) { s1g[row] = s1; s2g[row] = s2; }
        else {
            s1u[n] = s1;
            d1u[n] = s2 + bs[n] + bi[n];
        }
    }
}

// ---------------------------------------------------------------------------
// K1: fused stats + x->bf16 conversion + u-GEMM.  One wave = 16 tokens.
// (unchanged this round)
// ---------------------------------------------------------------------------
__global__ __launch_bounds__(256) void k_su(
    const float* __restrict__ x, const ushort_t* __restrict__ Wpsi,
    const float* __restrict__ s1u, const float* __restrict__ d1u,
    ushort_t* __restrict__ xb, float2* __restrict__ stats,
    float* __restrict__ u)
{
    __shared__ __attribute__((aligned(16))) ushort_t wlds[NS * 1032];
    int tid = threadIdx.x;
    for (int i = tid; i < 2048; i += 256) {        // 2048 x 16B = 32KB
        int e = i * 8; int rr = e >> 10; int c = e & 1023;
        *(uint4*)&wlds[rr * 1032 + c] = ((const uint4*)Wpsi)[i];
    }
    __syncthreads();

    int wv = tid >> 6, lane = tid & 63;
    int quad = lane >> 4, l15 = lane & 15;
    int t0 = blockIdx.x * 64 + wv * 16;
    const float* xrow = x + (size_t)(t0 + l15) * DM + quad * 8;
    ushort_t* xbrow = xb + (size_t)(t0 + l15) * DM + quad * 8;

    float s = 0.f, q = 0.f;
    f32x4 acc = {0.f, 0.f, 0.f, 0.f};
    for (int kk = 0; kk < 32; ++kk) {
        int k0 = kk * 32;
        float4 a0 = *(const float4*)(xrow + k0);
        float4 a1 = *(const float4*)(xrow + k0 + 4);
        s += a0.x + a0.y + a0.z + a0.w + a1.x + a1.y + a1.z + a1.w;
        q += a0.x * a0.x + a0.y * a0.y + a0.z * a0.z + a0.w * a0.w
           + a1.x * a1.x + a1.y * a1.y + a1.z * a1.z + a1.w * a1.w;
        union { uint4 u4; short8 s8; } ab;
        ab.u4 = cvt8u(a0, a1);
        *(uint4*)(xbrow + k0) = ab.u4;
        short8 b = *(const short8*)&wlds[l15 * 1032 + k0 + quad * 8];
        acc = __builtin_amdgcn_mfma_f32_16x16x32_bf16(ab.s8, b, acc, 0, 0, 0);
    }
    // full-row sums: reduce across the 4 lanes (bits 4,5) sharing each row
    s += __shfl_xor(s, 16); s += __shfl_xor(s, 32);
    q += __shfl_xor(q, 16); q += __shfl_xor(q, 32);
    float mu = s * (1.f / DM);
    float var = q * (1.f / DM) - mu * mu;
    float rs = rsqrtf(var + 1e-5f);
    float rsmu = rs * mu;
    if (lane < 16) stats[t0 + lane] = make_float2(rs, rsmu);

    float s1v = s1u[l15], d1v = d1u[l15];
#pragma unroll
    for (int r = 0; r < 4; r++) {
        int rowloc = quad * 4 + r;                 // C/D: row = quad*4+reg
        float rs_r = __shfl(rs, rowloc);
        float rsmu_r = __shfl(rsmu, rowloc);
        u[(size_t)(t0 + rowloc) * NS + l15] = rs_r * acc[r] - rsmu_r * s1v + d1v;
    }
}

// ---------------------------------------------------------------------------
// K2: recurrent scan, chunked-parallel with warmup (f32). (unchanged)
// ---------------------------------------------------------------------------
__global__ __launch_bounds__(64) void k_scan(
    const float* __restrict__ u, const float* __restrict__ A,
    float* __restrict__ H)
{
    __shared__ float Al[NS * NS];
    int tid = threadIdx.x;
    for (int i = tid; i < NS * NS; i += 64) Al[i] = A[i];
    __syncthreads();

    int chain = blockIdx.x * 64 + tid;
    int b = chain >> 8;            // 256 chunks per batch
    int ck = chain & 255;
    int s0 = ck << 4;
    int s = (ck == 0) ? 0 : s0 - 16;
    int send = s0 + 16;

    float h[16];
#pragma unroll
    for (int n = 0; n < 16; n++) h[n] = 0.f;

    const float4* up = (const float4*)(u + (size_t)b * SEQ * NS);
    float4* Hp = (float4*)(H + (size_t)b * SEQ * NS);

    for (; s < send; ++s) {
        float4 u0 = up[s * 4 + 0], u1 = up[s * 4 + 1];
        float4 u2 = up[s * 4 + 2], u3 = up[s * 4 + 3];
        float uu[16] = {u0.x, u0.y, u0.z, u0.w, u1.x, u1.y, u1.z, u1.w,
                        u2.x, u2.y, u2.z, u2.w, u3.x, u3.y, u3.z, u3.w};
        float hn[16];
#pragma unroll
        for (int n = 0; n < 16; n++) {
            float a = uu[n];
#pragma unroll
            for (int m = 0; m < 16; m++) a += Al[n * 16 + m] * h[m];
            float e = __expf(2.f * a);             // tanh = 1 - 2/(e^{2a}+1)
            hn[n] = 1.f - 2.f / (e + 1.f);
        }
#pragma unroll
        for (int n = 0; n < 16; n++) h[n] = hn[n];
        if (s >= s0) {
            Hp[s * 4 + 0] = make_float4(h[0], h[1], h[2], h[3]);
            Hp[s * 4 + 1] = make_float4(h[4], h[5], h[6], h[7]);
            Hp[s * 4 + 2] = make_float4(h[8], h[9], h[10], h[11]);
            Hp[s * 4 + 3] = make_float4(h[12], h[13], h[14], h[15]);
        }
    }
}

// ---------------------------------------------------------------------------
// K3: gate GEMM P = xb @ Wpg^T (M=32768, N=1024, K=1024) + fused epilogue.
// This round's restructure:
//  (1) XCD-coherent window mapping: tileM=(bid>>6)*8+(bid&7), tileN=(bid>>3)&7.
//      The 8 blocks sharing an A-tile have bids congruent mod 8 (same XCD
//      under round-robin dispatch) within one 64-bid window (temporally
//      adjacent) -> A-tile fetched once into that XCD's L2, reused 7x.
//      Wpg (2 MB) stays L2-resident.  Predicted FETCH_SIZE 292->~90 MB.
//  (2) Double-buffered LDS, prefetch-before-compute (T3-minimum 2-phase).
//      One __syncthreads per K-iter; its implicit vmcnt(0)+lgkmcnt(0) drain
//      is exactly the required sync (no inline-asm barriers -> no race risk).
//      Next tile's global_load_lds fly under current tile's ds_read+MFMA.
//  (3) XOR swizzle, both-sides-or-neither (rule #21): global SOURCE column
//      pre-swizzled (q ^= row&3), ds_read slot swizzled identically, LDS
//      dest stays linear for global_load_lds.  8-way -> 4-way conflicts.
//  (4) lH/lWo/lst LDS staging dropped; epilogue reads H/Wo/stats directly
//      (L2-hot float4).  LDS 37.9 KB -> 32 KB.
// ---------------------------------------------------------------------------
__global__ __launch_bounds__(256) void k_gate(
    const ushort_t* __restrict__ xb, const ushort_t* __restrict__ Wpg,
    const float* __restrict__ H, const float* __restrict__ Wo,
    const float* __restrict__ bo, const float* __restrict__ bg,
    const float* __restrict__ s1g, const float* __restrict__ s2g,
    const float2* __restrict__ stats, float* __restrict__ out)
{
    __shared__ __attribute__((aligned(16))) ushort_t lA[2][128 * 32]; // 2x8KB
    __shared__ __attribute__((aligned(16))) ushort_t lB[2][128 * 32]; // 2x8KB

    int tid = threadIdx.x;
    int bid = blockIdx.x;
    // XCD-coherent window mapping (bijective over 2048 blocks)
    int tileM = ((bid >> 6) * 8 + (bid & 7)) * 128;
    int tileN = ((bid >> 3) & 7) * 128;

    int lane = tid & 63, wv = tid >> 6;
    int wm = wv >> 1, wn = wv & 1;
    int quad = lane >> 4, l15 = lane & 15;

    // staging chunks: chunk c holds row (c>>2), 16B col-slot (c&3) of the
    // 128x32 tile; SOURCE column pre-swizzled by row&3 (involution).
    int c0 = tid, c1 = tid + 256;
    int r0 = c0 >> 2, r1 = c1 >> 2;
    int q0 = (c0 & 3) ^ (r0 & 3), q1 = (c1 & 3) ^ (r1 & 3);
    const ushort_t* Ab0 = xb + (size_t)(tileM + r0) * DM + q0 * 8;
    const ushort_t* Ab1 = xb + (size_t)(tileM + r1) * DM + q1 * 8;
    const ushort_t* Bb0 = Wpg + (size_t)(tileN + r0) * DM + q0 * 8;
    const ushort_t* Bb1 = Wpg + (size_t)(tileN + r1) * DM + q1 * 8;

    f32x4 acc[4][4];
#pragma unroll
    for (int i = 0; i < 4; i++)
#pragma unroll
        for (int j = 0; j < 4; j++) acc[i][j] = (f32x4){0.f, 0.f, 0.f, 0.f};

    // fragment-read offsets (ushort units), slot swizzled by row&3 = l15&3
    int qx = quad ^ (l15 & 3);
    int aoff = (wm * 64 + l15) * 32 + qx * 8;    // + mt*16*32
    int boff = (wn * 64 + l15) * 32 + qx * 8;    // + nt*16*32

    // prologue: stage tile 0 into buffer 0
    async_lds16(&lA[0][c0 * 8], Ab0);
    async_lds16(&lA[0][c1 * 8], Ab1);
    async_lds16(&lB[0][c0 * 8], Bb0);
    async_lds16(&lB[0][c1 * 8], Bb1);
    __syncthreads();

    for (int kk = 0; kk < 32; ++kk) {
        int cur = kk & 1;
        if (kk < 31) {                         // prefetch next tile first
            int nk = (kk + 1) * 32;
            async_lds16(&lA[cur ^ 1][c0 * 8], Ab0 + nk);
            async_lds16(&lA[cur ^ 1][c1 * 8], Ab1 + nk);
            async_lds16(&lB[cur ^ 1][c0 * 8], Bb0 + nk);
            async_lds16(&lB[cur ^ 1][c1 * 8], Bb1 + nk);
        }
        short8 af[4], bfr[4];
#pragma unroll
        for (int mt = 0; mt < 4; mt++)
            af[mt] = *(const short8*)&lA[cur][aoff + mt * 512];
#pragma unroll
        for (int nt = 0; nt < 4; nt++)
            bfr[nt] = *(const short8*)&lB[cur][boff + nt * 512];
#pragma unroll
        for (int mt = 0; mt < 4; mt++)
#pragma unroll
            for (int nt = 0; nt < 4; nt++)
                acc[mt][nt] = __builtin_amdgcn_mfma_f32_16x16x32_bf16(
                    af[mt], bfr[nt], acc[mt][nt], 0, 0, 0);
        __syncthreads();   // drains prefetch vmcnt + protects buffer swap
    }

    // ---- epilogue (H, Wo, stats direct from global — L2-hot) ----
    float wor[4][16], bo4[4], bg4[4], s1v[4], s2v[4];
#pragma unroll
    for (int nt = 0; nt < 4; nt++) {
        int e = tileN + wn * 64 + nt * 16 + l15;
        bo4[nt] = bo[e];
        bg4[nt] = bg[e];
        s1v[nt] = s1g[e];
        s2v[nt] = s2g[e];
        const float4* wop = (const float4*)(Wo + (size_t)e * NS);
#pragma unroll
        for (int k = 0; k < 4; k++) {
            float4 w4 = wop[k];
            wor[nt][k * 4 + 0] = w4.x; wor[nt][k * 4 + 1] = w4.y;
            wor[nt][k * 4 + 2] = w4.z; wor[nt][k * 4 + 3] = w4.w;
        }
    }
#pragma unroll
    for (int mt = 0; mt < 4; mt++) {
#pragma unroll
        for (int r = 0; r < 4; r++) {
            int t_loc = wm * 64 + mt * 16 + quad * 4 + r;
            size_t t = (size_t)(tileM + t_loc);
            float2 st = stats[t];
            const float4* hp = (const float4*)(H + t * NS);
            float hr[16];
#pragma unroll
            for (int k = 0; k < 4; k++) {
                float4 h4 = hp[k];
                hr[k * 4 + 0] = h4.x; hr[k * 4 + 1] = h4.y;
                hr[k * 4 + 2] = h4.z; hr[k * 4 + 3] = h4.w;
            }
            const ushort_t* xrow = xb + t * DM;   // residual from bf16 x (L2-hot)
            float* orow = out + t * DM;
#pragma unroll
            for (int nt = 0; nt < 4; nt++) {
                int e = tileN + wn * 64 + nt * 16 + l15;
                float g = st.x * acc[mt][nt][r] - st.y * s1v[nt] + s2v[nt] + bg4[nt];
                float sig = 1.f / (1.f + __expf(-g));
                float o = bo4[nt];
#pragma unroll
                for (int n = 0; n < 16; n++) o += hr[n] * wor[nt][n];
                orow[e] = o * sig + bf2f(xrow[e]);
            }
        }
    }
}

// ---------------------------------------------------------------------------
extern "C" void kernel_launch(void* const* d_in, const int* in_sizes, int n_in,
                              void* d_out, int out_size, void* d_ws, size_t ws_size,
                              hipStream_t stream)
{
    const float* x  = (const float*)d_in[0];
    const float* Ws = (const float*)d_in[1];
    const float* bs = (const float*)d_in[2];
    const float* Wi = (const float*)d_in[3];
    const float* bi = (const float*)d_in[4];
    const float* Wo = (const float*)d_in[5];
    const float* bo = (const float*)d_in[6];
    const float* Wg = (const float*)d_in[7];
    const float* bg = (const float*)d_in[8];
    const float* lw = (const float*)d_in[9];
    const float* lb = (const float*)d_in[10];
    const float* A  = (const float*)d_in[11];
    float* out = (float*)d_out;

    // ws layout (total ~73.7 MB)
    char* ws = (char*)d_ws;
    ushort_t* xb   = (ushort_t*)(ws);                 // 67,108,864 B (bf16 x)
    float*    u    = (float*)(ws + 67108864);         // 2,097,152 B
    float*    Hb   = (float*)(ws + 69206016);         // 2,097,152 B
    ushort_t* Wpg2 = (ushort_t*)(ws + 71303168);      // 2,097,152 B
    ushort_t* Wpsi = (ushort_t*)(ws + 73400320);      // 32,768 B
    float2*   st   = (float2*)(ws + 73433088);        // 262,144 B
    float*    s1g  = (float*)(ws + 73695232);         // 4,096 B
    float*    s2g  = (float*)(ws + 73699328);         // 4,096 B
    float*    s1u  = (float*)(ws + 73703424);         // 64 B
    float*    d1u  = (float*)(ws + 73703488);         // 64 B

    k_prep<<<260, 256, 0, stream>>>(Wg, Ws, Wi, lw, lb, bs, bi,
                                    Wpg2, Wpsi, s1g, s2g, s1u, d1u);
    k_su<<<TOK / 64, 256, 0, stream>>>(x, Wpsi, s1u, d1u, xb, st, u);
    k_scan<<<32, 64, 0, stream>>>(u, A, Hb);
    k_gate<<<(TOK / 128) * (DM / 128), 256, 0, stream>>>(
        xb, Wpg2, Hb, Wo, bo, bg, s1g, s2g, st, out);
}